// Round 11
// baseline (289.270 us; speedup 1.0000x reference)
//
#include <hip/hip_runtime.h>

typedef unsigned short ushort_t;
typedef unsigned int uint_t;

typedef short bf16x8 __attribute__((ext_vector_type(8)));
typedef float f32x4 __attribute__((ext_vector_type(4)));

#define MFMA16(a, b, c) __builtin_amdgcn_mfma_f32_16x16x32_bf16(a, b, c, 0, 0, 0)

__device__ __forceinline__ ushort_t f2bf(float f) {
    uint_t u = __float_as_uint(f);
    u += 0x7fffu + ((u >> 16) & 1u);   // RNE
    return (ushort_t)(u >> 16);
}
__device__ __forceinline__ float bf2f(ushort_t h) {
    return __uint_as_float(((uint_t)h) << 16);
}

// ---------------- K0: fused prep (R10 version — verified).
// blocks 0..7: const_h wave-parallel; 8..135: Wa->bf16 blocked;
// 136..151: Ws1[:, :256] -> bf16 hi/lo blocked; 152..215: zero u_i.
// blocked flat (in 8-elem units): ((row/16)*32 + k/8)*16 + row%16
__global__ void k_prep(const float* __restrict__ Ws1, const float* __restrict__ bs1,
                       const float* __restrict__ virt, const float* __restrict__ Wa,
                       float* __restrict__ consth, ushort_t* __restrict__ wa_b,
                       ushort_t* __restrict__ ws1h, ushort_t* __restrict__ ws1l,
                       float* __restrict__ u_i) {
    int b = blockIdx.x;
    if (b < 8) {
        int w = threadIdx.x >> 6, lane = threadIdx.x & 63;
#pragma unroll
        for (int i = 0; i < 4; ++i) {
            int row = b * 16 + w * 4 + i;
            const float* rp = Ws1 + row * 512 + 256;
            float4 v = *(const float4*)(rp + lane * 4);
            float4 vv = *(const float4*)(virt + lane * 4);
            float s = v.x * vv.x + v.y * vv.y + v.z * vv.z + v.w * vv.w;
            s += __shfl_xor(s, 1, 64);
            s += __shfl_xor(s, 2, 64);
            s += __shfl_xor(s, 4, 64);
            s += __shfl_xor(s, 8, 64);
            s += __shfl_xor(s, 16, 64);
            s += __shfl_xor(s, 32, 64);
            if (lane == 0) consth[row] = bs1[row] + s;
        }
        return;
    }
    if (b >= 152) {
        int t = (b - 152) * 1024 + threadIdx.x * 4;
        float4 z = {0.f, 0.f, 0.f, 0.f};
        *(float4*)(u_i + t) = z;
        return;
    }
    const float* src;
    int src_stride, tid;
    ushort_t *dhi, *dlo;
    if (b <= 135) {
        tid = (b - 8) * 256 + threadIdx.x;   // 1024 rows * 32 = 32768 tids
        src = Wa; src_stride = 256; dhi = wa_b; dlo = nullptr;
    } else {
        tid = (b - 136) * 256 + threadIdx.x; // 128 rows * 32 = 4096 tids
        src = Ws1; src_stride = 512; dhi = ws1h; dlo = ws1l;
    }
    int pl = tid & 15, kc = (tid >> 4) & 31, pt = tid >> 9;
    int row = pt * 16 + pl;
    const float* s = src + (size_t)row * src_stride + kc * 8;
    ushort_t hs[8], ls[8];
#pragma unroll
    for (int j = 0; j < 8; ++j) {
        float v = s[j];
        ushort_t h = f2bf(v);
        hs[j] = h;
        ls[j] = f2bf(v - bf2f(h));
    }
    uint4 hv;
    hv.x = hs[0] | ((uint_t)hs[1] << 16); hv.y = hs[2] | ((uint_t)hs[3] << 16);
    hv.z = hs[4] | ((uint_t)hs[5] << 16); hv.w = hs[6] | ((uint_t)hs[7] << 16);
    *(uint4*)(dhi + (size_t)tid * 8) = hv;
    if (dlo) {
        uint4 lv;
        lv.x = ls[0] | ((uint_t)ls[1] << 16); lv.y = ls[2] | ((uint_t)ls[3] << 16);
        lv.z = ls[4] | ((uint_t)ls[5] << 16); lv.w = ls[6] | ((uint_t)ls[7] << 16);
        *(uint4*)(dlo + (size_t)tid * 8) = lv;
    }
}

// ---------------- K1a: embed (gather+trig) + split-bf16 struct head + sigmoid.
// Writes hi-fragments (blocked, 32 KB/block contiguous) to ghi for K1b, and A_hat.
// (unchanged from R4 — verified)
__global__ __launch_bounds__(256, 2) void k_embed(
    const int* __restrict__ q_seq, const int* __restrict__ r_seq,
    const float* __restrict__ t_seq, const float* __restrict__ q_tab,
    const float* __restrict__ r_tab,
    const ushort_t* __restrict__ ws1h, const ushort_t* __restrict__ ws1l,
    const float* __restrict__ consth, const float* __restrict__ Ws2,
    const float* __restrict__ bs2, const float* __restrict__ mask,
    float* __restrict__ out_ahat, ushort_t* __restrict__ ghi) {
    __shared__ __align__(16) ushort_t sAhi[16384];   // 64 pos x 256 k (hi), 32 KB
    __shared__ __align__(16) ushort_t sAlo[8192];    // 64 pos x 128 k (lo half), 16 KB
    __shared__ float sdiv[128];
    __shared__ float sLogit[64];
    int tid = threadIdx.x;
    if (tid < 128) sdiv[tid] = __expf((float)tid * -0.07195578415606394f); // -ln(10000)/128
    if (tid < 64) sLogit[tid] = 0.0f;
    int w = tid >> 6, lane = tid & 63;
    int pl = lane & 15, kq = lane >> 4;
    int nl = pl;
    int p0 = blockIdx.x * 64;
    int p = p0 + w * 16 + pl;
    int qv = q_seq[p];          // lanes with same pl share qv (same p)
    int rr = r_seq[p];
    float tt = t_seq[p];
    const float* grow = q_tab + (size_t)qv * 256;
    const float* rrow = r_tab + (size_t)rr * 256;
    uint4* gdst = (uint4*)(ghi + (size_t)blockIdx.x * 16384);
    __syncthreads();  // sdiv + sLogit ready
    // ---- gather + trig -> fragments to LDS (MFMA A-layout) + hi copy to global
    uint4 lo_hold[4];
#pragma unroll
    for (int it = 0; it < 8; ++it) {
        int kc = it * 4 + kq;
        int k0 = kc * 8;
        float4 qa = *(const float4*)(grow + kc * 8);
        float4 qb = *(const float4*)(grow + kc * 8 + 4);
        float4 ra = *(const float4*)(rrow + kc * 8);
        float4 rb = *(const float4*)(rrow + kc * 8 + 4);
        float v[8] = {qa.x + ra.x, qa.y + ra.y, qa.z + ra.z, qa.w + ra.w,
                      qb.x + rb.x, qb.y + rb.y, qb.z + rb.z, qb.w + rb.w};
        bool iscos = (kc >= 16);
#pragma unroll
        for (int j = 0; j < 8; ++j) {
            float ang = tt * sdiv[(k0 + j) & 127];
            v[j] += iscos ? __cosf(ang) : __sinf(ang);
        }
        ushort_t hs[8], ls[8];
#pragma unroll
        for (int j = 0; j < 8; ++j) {
            ushort_t h = f2bf(v[j]);
            hs[j] = h;
            ls[j] = (ushort_t)(__float_as_uint(v[j] - bf2f(h)) >> 16);
        }
        uint4 hv, lv;
        hv.x = hs[0] | ((uint_t)hs[1] << 16); hv.y = hs[2] | ((uint_t)hs[3] << 16);
        hv.z = hs[4] | ((uint_t)hs[5] << 16); hv.w = hs[6] | ((uint_t)hs[7] << 16);
        lv.x = ls[0] | ((uint_t)ls[1] << 16); lv.y = ls[2] | ((uint_t)ls[3] << 16);
        lv.z = ls[4] | ((uint_t)ls[5] << 16); lv.w = ls[6] | ((uint_t)ls[7] << 16);
        int unit = (w * 32 + kc) * 16 + pl;
        *(uint4*)(sAhi + unit * 8) = hv;
        gdst[unit] = hv;
        if (it < 4) {
            *(uint4*)(sAlo + ((w * 16 + kc) * 16 + pl) * 8) = lv;   // kc in 0..15
        } else {
            lo_hold[it - 4] = lv;
        }
    }
    __syncthreads();  // fragments visible block-wide
    // ---- struct head (split-bf16, 3 MFMAs), two k-phases over the halved sAlo
    {
        f32x4 acc[4][2];
        f32x4 z4 = {0.f, 0.f, 0.f, 0.f};
#pragma unroll
        for (int mt = 0; mt < 4; ++mt)
#pragma unroll
            for (int nt = 0; nt < 2; ++nt) acc[mt][nt] = z4;
#pragma unroll
        for (int ks = 0; ks < 8; ++ks) {
            if (ks == 4) {
                // swap in the second lo half (barrier: all phase-A sAlo reads done)
                __syncthreads();
#pragma unroll
                for (int it = 4; it < 8; ++it) {
                    int kc = it * 4 + kq;
                    *(uint4*)(sAlo + ((w * 16 + (kc - 16)) * 16 + pl) * 8) = lo_hold[it - 4];
                }
                __syncthreads();
            }
            bf16x8 bh[2], bl[2];
#pragma unroll
            for (int nt = 0; nt < 2; ++nt) {
                int off = (((w * 2 + nt) * 32 + ks * 4 + kq) * 16 + nl) * 8;
                bh[nt] = *(const bf16x8*)(ws1h + off);
                bl[nt] = *(const bf16x8*)(ws1l + off);
            }
#pragma unroll
            for (int mth = 0; mth < 2; ++mth) {
                bf16x8 ahi[2], alo[2];
#pragma unroll
                for (int mi = 0; mi < 2; ++mi) {
                    int mt = mth * 2 + mi;
                    ahi[mi] = *(const bf16x8*)&sAhi[((mt * 32 + ks * 4 + kq) * 16 + nl) * 8];
                    alo[mi] = *(const bf16x8*)&sAlo[((mt * 16 + (ks & 3) * 4 + kq) * 16 + nl) * 8];
                }
#pragma unroll
                for (int mi = 0; mi < 2; ++mi)
#pragma unroll
                    for (int nt = 0; nt < 2; ++nt) {
                        int mt = mth * 2 + mi;
                        acc[mt][nt] = MFMA16(ahi[mi], bh[nt], acc[mt][nt]);
                        acc[mt][nt] = MFMA16(alo[mi], bh[nt], acc[mt][nt]);
                        acc[mt][nt] = MFMA16(ahi[mi], bl[nt], acc[mt][nt]);
                    }
            }
        }
        // epilogue: hdn = leaky(acc + const_h); partial logits = hdn * Ws2
        float ps[4][4];
#pragma unroll
        for (int mt = 0; mt < 4; ++mt)
#pragma unroll
            for (int r = 0; r < 4; ++r) ps[mt][r] = 0.f;
#pragma unroll
        for (int nt = 0; nt < 2; ++nt) {
            int ng = w * 32 + nt * 16 + nl;
            float chv = consth[ng], w2 = Ws2[ng];
#pragma unroll
            for (int mt = 0; mt < 4; ++mt)
#pragma unroll
                for (int r = 0; r < 4; ++r) {
                    float v = acc[mt][nt][r] + chv;
                    v = fmaxf(v, 0.2f * v);
                    ps[mt][r] += v * w2;
                }
        }
#pragma unroll
        for (int mt = 0; mt < 4; ++mt)
#pragma unroll
            for (int r = 0; r < 4; ++r) {
                float x = ps[mt][r];
                x += __shfl_xor(x, 1, 64);
                x += __shfl_xor(x, 2, 64);
                x += __shfl_xor(x, 4, 64);
                x += __shfl_xor(x, 8, 64);
                ps[mt][r] = x;
            }
        if (nl == 0) {
#pragma unroll
            for (int mt = 0; mt < 4; ++mt)
#pragma unroll
                for (int r = 0; r < 4; ++r)
                    atomicAdd(&sLogit[mt * 16 + kq * 4 + r], ps[mt][r]);
        }
    }
    __syncthreads();
    if (tid < 64) {
        int pp = p0 + tid;
        float lg = sLogit[tid] + bs2[0];
        float y = lg * 100.0f;
        y = fminf(fmaxf(y, -60.f), 60.f);
        float a = 1.0f / (1.0f + expf(-y));
        out_ahat[pp] = a * mask[pp];
    }
}

// ---------------- K1b v7: Wa GEMM + aggregator, INVERTED TILE: 512 pos x 128 N.
// R4's 64x1024 tile reads all 512 KB of B per block -> 1.06 GB L2 traffic with
// zero L1 reuse on the streamed operand. Here the 64 KB B-slice (contiguous in
// the blocked layout) lives in LDS for the whole block; A streams from ghi with
// the SAME depth-1 parity dbuf pattern R4 verified (operands swapped). All 4
// waves read identical A addresses -> 3/4 L1 hits. Position-reduction folds
// into s_nt[2] across the 8 subchunks -> 1 atomic per (N-col) per block
// (4-way contention vs 32). Traffic: (256 KB A + 64 KB B) x 2048 = 640 MB (-40%).
// Regs: afr[2][4]=32 + acc[4][2]=32 AGPR + transients ~= R4's 112+32 budget.
// Spill sentinel: WRITE_SIZE > 20 MB -> k_wa is pinned at R4; revert.
__global__ __launch_bounds__(256, 2) void k_wa(
    const ushort_t* __restrict__ ghi, const float* __restrict__ out_ahat,
    const ushort_t* __restrict__ wa_b, const float* __restrict__ ba,
    float* __restrict__ u_i) {
    __shared__ __align__(16) ushort_t sB[32768];   // 128 N x 256 K blocked, 64 KB
    __shared__ float sAh[512];
    int tid = threadIdx.x;
    int nslice = blockIdx.x >> 8;        // 0..7  (N-cols [nslice*128, +128))
    int pblk = blockIdx.x & 255;         // 0..255 (positions [pblk*512, +512))
    int P0 = pblk * 512;
    // stage B slice: 64 KB contiguous (blocked layout is row-tile-major)
    {
        const uint4* src = (const uint4*)(wa_b + (size_t)nslice * 32768);
        uint4* dst = (uint4*)sB;
#pragma unroll
        for (int i = 0; i < 16; ++i) dst[tid + i * 256] = src[tid + i * 256];
    }
    sAh[tid] = out_ahat[P0 + tid];
    sAh[tid + 256] = out_ahat[P0 + tid + 256];
    __syncthreads();
    int w = tid >> 6, lane = tid & 63;
    int kq = lane >> 4, nl = lane & 15;
    // per-wave N-cols: [nslice*128 + w*32, +32) via nt in {0,1}
    float ban[2];
#pragma unroll
    for (int nt = 0; nt < 2; ++nt)
        ban[nt] = ba[nslice * 128 + w * 32 + nt * 16 + nl];
    float s_nt[2] = {0.f, 0.f};
#pragma unroll 1
    for (int c = 0; c < 8; ++c) {
        // A fragments for 64 positions [P0 + c*64, +64), streamed with parity dbuf.
        // elem offset = mt*4096 + ks*512 + (kq*128 + nl*8 = lane*8)
        const ushort_t* gA = ghi + ((size_t)(pblk * 8 + c)) * 16384 + lane * 8;
        f32x4 acc[4][2];
        bf16x8 afr[2][4];
#pragma unroll
        for (int mt = 0; mt < 4; ++mt)
            afr[0][mt] = *(const bf16x8*)(gA + mt * 4096);
#pragma unroll
        for (int ks = 0; ks < 8; ++ks) {
            int cur = ks & 1, nxt = cur ^ 1;
            if (ks < 7) {
#pragma unroll
                for (int mt = 0; mt < 4; ++mt)
                    afr[nxt][mt] = *(const bf16x8*)(gA + mt * 4096 + (ks + 1) * 512);
            }
            bf16x8 b_[2];
#pragma unroll
            for (int nt = 0; nt < 2; ++nt)
                b_[nt] = *(const bf16x8*)&sB[(w * 2 + nt) * 4096 + ks * 512 + lane * 8];
            if (ks == 0) {
                f32x4 z4 = {0.f, 0.f, 0.f, 0.f};
#pragma unroll
                for (int mt = 0; mt < 4; ++mt)
#pragma unroll
                    for (int nt = 0; nt < 2; ++nt)
                        acc[mt][nt] = MFMA16(afr[0][mt], b_[nt], z4);
            } else {
#pragma unroll
                for (int mt = 0; mt < 4; ++mt)
#pragma unroll
                    for (int nt = 0; nt < 2; ++nt)
                        acc[mt][nt] = MFMA16(afr[cur][mt], b_[nt], acc[mt][nt]);
            }
        }
        // fold this subchunk: leaky(acc+ba)*A_hat summed over its 64 positions
        float ah[16];
#pragma unroll
        for (int mt = 0; mt < 4; ++mt)
#pragma unroll
            for (int r = 0; r < 4; ++r)
                ah[mt * 4 + r] = sAh[c * 64 + mt * 16 + kq * 4 + r];
#pragma unroll
        for (int nt = 0; nt < 2; ++nt) {
            float s = 0.f;
#pragma unroll
            for (int mt = 0; mt < 4; ++mt)
#pragma unroll
                for (int r = 0; r < 4; ++r) {
                    float v = acc[mt][nt][r] + ban[nt];
                    v = fmaxf(v, 0.2f * v);
                    s += v * ah[mt * 4 + r];
                }
            s_nt[nt] += s;
        }
    }
    // final reduce over kq groups + one atomic per N-col
    int seq = P0 >> 11;
#pragma unroll
    for (int nt = 0; nt < 2; ++nt) {
        float s = s_nt[nt];
        s += __shfl_xor(s, 16, 64);
        s += __shfl_xor(s, 32, 64);
        if (kq == 0) {
            int ng = nslice * 128 + w * 32 + nt * 16 + nl;
            atomicAdd(&u_i[seq * 1024 + ng], s);
        }
    }
}

// ---------------- Fallback: the verified R1 fully-fused kernel (used only if
// the workspace is too small for ghi).
__global__ __launch_bounds__(256, 2) void k_fused_fb(
    const int* __restrict__ q_seq, const int* __restrict__ r_seq,
    const float* __restrict__ t_seq, const float* __restrict__ q_tab,
    const float* __restrict__ r_tab,
    const ushort_t* __restrict__ ws1h, const ushort_t* __restrict__ ws1l,
    const float* __restrict__ consth, const float* __restrict__ Ws2,
    const float* __restrict__ bs2, const float* __restrict__ mask,
    const ushort_t* __restrict__ wa_b, const float* __restrict__ ba,
    float* __restrict__ out_ahat, float* __restrict__ u_i) {
    __shared__ __align__(16) ushort_t sAhi[16384];
    __shared__ __align__(16) ushort_t sAlo[16384];
    __shared__ float sdiv[128];
    __shared__ float sLogit[64];
    __shared__ float sAh[64];
    int tid = threadIdx.x;
    if (tid < 128) sdiv[tid] = __expf((float)tid * -0.07195578415606394f);
    if (tid < 64) sLogit[tid] = 0.0f;
    int w = tid >> 6, lane = tid & 63;
    int pl = lane & 15, kq = lane >> 4;
    int nl = pl;
    int p0 = blockIdx.x * 64;
    int p = p0 + w * 16 + pl;
    int qv = q_seq[p];
    int rr = r_seq[p];
    float tt = t_seq[p];
    const float* grow = q_tab + (size_t)qv * 256;
    const float* rrow = r_tab + (size_t)rr * 256;
    __syncthreads();
#pragma unroll
    for (int it = 0; it < 8; ++it) {
        int kc = it * 4 + kq;
        int k0 = kc * 8;
        float4 qa = *(const float4*)(grow + kc * 8);
        float4 qb = *(const float4*)(grow + kc * 8 + 4);
        float4 ra = *(const float4*)(rrow + kc * 8);
        float4 rb = *(const float4*)(rrow + kc * 8 + 4);
        float v[8] = {qa.x + ra.x, qa.y + ra.y, qa.z + ra.z, qa.w + ra.w,
                      qb.x + rb.x, qb.y + rb.y, qb.z + rb.z, qb.w + rb.w};
        bool iscos = (kc >= 16);
#pragma unroll
        for (int j = 0; j < 8; ++j) {
            float ang = tt * sdiv[(k0 + j) & 127];
            v[j] += iscos ? __cosf(ang) : __sinf(ang);
        }
        ushort_t hs[8], ls[8];
#pragma unroll
        for (int j = 0; j < 8; ++j) {
            ushort_t h = f2bf(v[j]);
            hs[j] = h;
            ls[j] = (ushort_t)(__float_as_uint(v[j] - bf2f(h)) >> 16);
        }
        uint4 hv, lv;
        hv.x = hs[0] | ((uint_t)hs[1] << 16); hv.y = hs[2] | ((uint_t)hs[3] << 16);
        hv.z = hs[4] | ((uint_t)hs[5] << 16); hv.w = hs[6] | ((uint_t)hs[7] << 16);
        lv.x = ls[0] | ((uint_t)ls[1] << 16); lv.y = ls[2] | ((uint_t)ls[3] << 16);
        lv.z = ls[4] | ((uint_t)ls[5] << 16); lv.w = ls[6] | ((uint_t)ls[7] << 16);
        int loff = ((w * 32 + kc) * 16 + pl) * 8;
        *(uint4*)(sAhi + loff) = hv;
        *(uint4*)(sAlo + loff) = lv;
    }
    __syncthreads();
    {
        f32x4 acc[4][2];
        f32x4 z4 = {0.f, 0.f, 0.f, 0.f};
#pragma unroll
        for (int mt = 0; mt < 4; ++mt)
#pragma unroll
            for (int nt = 0; nt < 2; ++nt) acc[mt][nt] = z4;
        bf16x8 bh[2][2], bl[2][2];
#pragma unroll
        for (int nt = 0; nt < 2; ++nt) {
            int off = (((w * 2 + nt) * 32 + kq) * 16 + nl) * 8;
            bh[0][nt] = *(const bf16x8*)(ws1h + off);
            bl[0][nt] = *(const bf16x8*)(ws1l + off);
        }
#pragma unroll
        for (int ks = 0; ks < 8; ++ks) {
            int cur = ks & 1, nxt = cur ^ 1;
            if (ks < 7) {
#pragma unroll
                for (int nt = 0; nt < 2; ++nt) {
                    int off = (((w * 2 + nt) * 32 + (ks + 1) * 4 + kq) * 16 + nl) * 8;
                    bh[nxt][nt] = *(const bf16x8*)(ws1h + off);
                    bl[nxt][nt] = *(const bf16x8*)(ws1l + off);
                }
            }
            bf16x8 ahi[4], alo[4];
#pragma unroll
            for (int mt = 0; mt < 4; ++mt) {
                int off = ((mt * 32 + ks * 4 + kq) * 16 + nl) * 8;
                ahi[mt] = *(const bf16x8*)&sAhi[off];
                alo[mt] = *(const bf16x8*)&sAlo[off];
            }
#pragma unroll
            for (int mt = 0; mt < 4; ++mt)
#pragma unroll
                for (int nt = 0; nt < 2; ++nt) {
                    acc[mt][nt] = MFMA16(ahi[mt], bh[cur][nt], acc[mt][nt]);
                    acc[mt][nt] = MFMA16(alo[mt], bh[cur][nt], acc[mt][nt]);
                    acc[mt][nt] = MFMA16(ahi[mt], bl[cur][nt], acc[mt][nt]);
                }
        }
        float ps[4][4];
#pragma unroll
        for (int mt = 0; mt < 4; ++mt)
#pragma unroll
            for (int r = 0; r < 4; ++r) ps[mt][r] = 0.f;
#pragma unroll
        for (int nt = 0; nt < 2; ++nt) {
            int ng = w * 32 + nt * 16 + nl;
            float chv = consth[ng], w2 = Ws2[ng];
#pragma unroll
            for (int mt = 0; mt < 4; ++mt)
#pragma unroll
                for (int r = 0; r < 4; ++r) {
                    float v = acc[mt][nt][r] + chv;
                    v = fmaxf(v, 0.2f * v);
                    ps[mt][r] += v * w2;
                }
        }
#pragma unroll
        for (int mt = 0; mt < 4; ++mt)
#pragma unroll
            for (int r = 0; r < 4; ++r) {
                float x = ps[mt][r];
                x += __shfl_xor(x, 1, 64);
                x += __shfl_xor(x, 2, 64);
                x += __shfl_xor(x, 4, 64);
                x += __shfl_xor(x, 8, 64);
                ps[mt][r] = x;
            }
        if (nl == 0) {
#pragma unroll
            for (int mt = 0; mt < 4; ++mt)
#pragma unroll
                for (int r = 0; r < 4; ++r)
                    atomicAdd(&sLogit[mt * 16 + kq * 4 + r], ps[mt][r]);
        }
    }
    __syncthreads();
    if (tid < 64) {
        int pp = p0 + tid;
        float lg = sLogit[tid] + bs2[0];
        float y = lg * 100.0f;
        y = fminf(fmaxf(y, -60.f), 60.f);
        float a = 1.0f / (1.0f + expf(-y));
        float av = a * mask[pp];
        out_ahat[pp] = av;
        sAh[tid] = av;
    }
    __syncthreads();
    {
        float ah[16];
#pragma unroll
        for (int mt = 0; mt < 4; ++mt)
#pragma unroll
            for (int r = 0; r < 4; ++r) ah[mt * 4 + r] = sAh[mt * 16 + kq * 4 + r];
        int bidx = p0 >> 11;
#pragma unroll 1
        for (int nblk = 0; nblk < 4; ++nblk) {
#pragma unroll 1
            for (int hf = 0; hf < 2; ++hf) {
                const ushort_t* gB = wa_b + (size_t)(w * 16 + nblk * 4 + hf * 2) * 4096 + lane * 8;
                f32x4 acc[4][2];
                bf16x8 bfr[2][2];
#pragma unroll
                for (int nt = 0; nt < 2; ++nt)
                    bfr[0][nt] = *(const bf16x8*)(gB + nt * 4096);
#pragma unroll
                for (int ks = 0; ks < 8; ++ks) {
                    int cur = ks & 1, nxt = cur ^ 1;
                    if (ks < 7) {
#pragma unroll
                        for (int nt = 0; nt < 2; ++nt)
                            bfr[nxt][nt] = *(const bf16x8*)(gB + nt * 4096 + (ks + 1) * 512);
                    }
                    bf16x8 a_[4];
#pragma unroll
                    for (int mt = 0; mt < 4; ++mt)
                        a_[mt] = *(const bf16x8*)&sAhi[((mt * 32 + ks * 4 + kq) * 16 + nl) * 8];
                    if (ks == 0) {
                        f32x4 z4 = {0.f, 0.f, 0.f, 0.f};
#pragma unroll
                        for (int mt = 0; mt < 4; ++mt)
#pragma unroll
                            for (int nt = 0; nt < 2; ++nt)
                                acc[mt][nt] = MFMA16(a_[mt], bfr[0][nt], z4);
                    } else {
#pragma unroll
                        for (int mt = 0; mt < 4; ++mt)
#pragma unroll
                            for (int nt = 0; nt < 2; ++nt)
                                acc[mt][nt] = MFMA16(a_[mt], bfr[cur][nt], acc[mt][nt]);
                    }
                }
#pragma unroll
                for (int nt = 0; nt < 2; ++nt) {
                    int ng = w * 256 + nblk * 64 + (hf * 2 + nt) * 16 + nl;
                    float ban = ba[ng];
                    float s = 0.f;
#pragma unroll
                    for (int mt = 0; mt < 4; ++mt)
#pragma unroll
                        for (int r = 0; r < 4; ++r) {
                            float v = acc[mt][nt][r] + ban;
                            v = fmaxf(v, 0.2f * v);
                            s += v * ah[mt * 4 + r];
                        }
                    s += __shfl_xor(s, 16, 64);
                    s += __shfl_xor(s, 32, 64);
                    if (kq == 0) atomicAdd(&u_i[bidx * 1024 + ng], s);
                }
            }
        }
    }
}

extern "C" void kernel_launch(void* const* d_in, const int* in_sizes, int n_in,
                              void* d_out, int out_size, void* d_ws, size_t ws_size,
                              hipStream_t stream) {
    const int* q_seq = (const int*)d_in[0];
    const int* r_seq = (const int*)d_in[1];
    const float* t_seq = (const float*)d_in[2];
    const float* mask = (const float*)d_in[3];
    const float* q_tab = (const float*)d_in[4];
    const float* r_tab = (const float*)d_in[5];
    const float* virt = (const float*)d_in[6];
    const float* Ws1 = (const float*)d_in[7];
    const float* bs1 = (const float*)d_in[8];
    const float* Ws2 = (const float*)d_in[9];
    const float* bs2 = (const float*)d_in[10];
    const float* Wa = (const float*)d_in[11];
    const float* ba = (const float*)d_in[12];
    float* out = (float*)d_out;

    // ws layout
    ushort_t* wa_b = (ushort_t*)d_ws;            // 1024*256 bf16 blocked (512 KB)
    ushort_t* ws1h = wa_b + 262144;              // 128*256 bf16 blocked (64 KB)
    ushort_t* ws1l = ws1h + 32768;               // 64 KB
    float* ch = (float*)(ws1l + 32768);          // 128 f32 (512 B)
    ushort_t* ghi = (ushort_t*)(ch + 128);       // 131072*256 bf16 blocked (64 MB)
    const size_t need = 524288 + 65536 + 65536 + 512 + 67108864;

    hipLaunchKernelGGL(k_prep, dim3(216), dim3(256), 0, stream,
                       Ws1, bs1, virt, Wa, ch, wa_b, ws1h, ws1l, out);
    if (ws_size >= need) {
        hipLaunchKernelGGL(k_embed, dim3(2048), dim3(256), 0, stream,
                           q_seq, r_seq, t_seq, q_tab, r_tab, ws1h, ws1l, ch, Ws2,
                           bs2, mask, out + 65536, ghi);
        hipLaunchKernelGGL(k_wa, dim3(2048), dim3(256), 0, stream,
                           ghi, out + 65536, wa_b, ba, out);
    } else {
        hipLaunchKernelGGL(k_fused_fb, dim3(2048), dim3(256), 0, stream,
                           q_seq, r_seq, t_seq, q_tab, r_tab, ws1h, ws1l, ch, Ws2,
                           bs2, mask, wa_b, ba, out + 65536, out);
    }
}

// Round 12
// 242.265 us; speedup vs baseline: 1.1940x; 1.1940x over previous
//
#include <hip/hip_runtime.h>

typedef unsigned short ushort_t;
typedef unsigned int uint_t;

typedef short bf16x8 __attribute__((ext_vector_type(8)));
typedef float f32x4 __attribute__((ext_vector_type(4)));

#define MFMA16(a, b, c) __builtin_amdgcn_mfma_f32_16x16x32_bf16(a, b, c, 0, 0, 0)

__device__ __forceinline__ ushort_t f2bf(float f) {
    uint_t u = __float_as_uint(f);
    u += 0x7fffu + ((u >> 16) & 1u);   // RNE
    return (ushort_t)(u >> 16);
}
__device__ __forceinline__ float bf2f(ushort_t h) {
    return __uint_as_float(((uint_t)h) << 16);
}

// ---------------- K0: fused prep (R10 version — verified).
// blocks 0..7: const_h wave-parallel; 8..135: Wa->bf16 blocked;
// 136..151: Ws1[:, :256] -> bf16 hi/lo blocked; 152..215: zero u_i.
// blocked flat (in 8-elem units): ((row/16)*32 + k/8)*16 + row%16
__global__ void k_prep(const float* __restrict__ Ws1, const float* __restrict__ bs1,
                       const float* __restrict__ virt, const float* __restrict__ Wa,
                       float* __restrict__ consth, ushort_t* __restrict__ wa_b,
                       ushort_t* __restrict__ ws1h, ushort_t* __restrict__ ws1l,
                       float* __restrict__ u_i) {
    int b = blockIdx.x;
    if (b < 8) {
        int w = threadIdx.x >> 6, lane = threadIdx.x & 63;
#pragma unroll
        for (int i = 0; i < 4; ++i) {
            int row = b * 16 + w * 4 + i;
            const float* rp = Ws1 + row * 512 + 256;
            float4 v = *(const float4*)(rp + lane * 4);
            float4 vv = *(const float4*)(virt + lane * 4);
            float s = v.x * vv.x + v.y * vv.y + v.z * vv.z + v.w * vv.w;
            s += __shfl_xor(s, 1, 64);
            s += __shfl_xor(s, 2, 64);
            s += __shfl_xor(s, 4, 64);
            s += __shfl_xor(s, 8, 64);
            s += __shfl_xor(s, 16, 64);
            s += __shfl_xor(s, 32, 64);
            if (lane == 0) consth[row] = bs1[row] + s;
        }
        return;
    }
    if (b >= 152) {
        int t = (b - 152) * 1024 + threadIdx.x * 4;
        float4 z = {0.f, 0.f, 0.f, 0.f};
        *(float4*)(u_i + t) = z;
        return;
    }
    const float* src;
    int src_stride, tid;
    ushort_t *dhi, *dlo;
    if (b <= 135) {
        tid = (b - 8) * 256 + threadIdx.x;   // 1024 rows * 32 = 32768 tids
        src = Wa; src_stride = 256; dhi = wa_b; dlo = nullptr;
    } else {
        tid = (b - 136) * 256 + threadIdx.x; // 128 rows * 32 = 4096 tids
        src = Ws1; src_stride = 512; dhi = ws1h; dlo = ws1l;
    }
    int pl = tid & 15, kc = (tid >> 4) & 31, pt = tid >> 9;
    int row = pt * 16 + pl;
    const float* s = src + (size_t)row * src_stride + kc * 8;
    ushort_t hs[8], ls[8];
#pragma unroll
    for (int j = 0; j < 8; ++j) {
        float v = s[j];
        ushort_t h = f2bf(v);
        hs[j] = h;
        ls[j] = f2bf(v - bf2f(h));
    }
    uint4 hv;
    hv.x = hs[0] | ((uint_t)hs[1] << 16); hv.y = hs[2] | ((uint_t)hs[3] << 16);
    hv.z = hs[4] | ((uint_t)hs[5] << 16); hv.w = hs[6] | ((uint_t)hs[7] << 16);
    *(uint4*)(dhi + (size_t)tid * 8) = hv;
    if (dlo) {
        uint4 lv;
        lv.x = ls[0] | ((uint_t)ls[1] << 16); lv.y = ls[2] | ((uint_t)ls[3] << 16);
        lv.z = ls[4] | ((uint_t)ls[5] << 16); lv.w = ls[6] | ((uint_t)ls[7] << 16);
        *(uint4*)(dlo + (size_t)tid * 8) = lv;
    }
}

// ---------------- K1a: embed (gather+trig) + split-bf16 struct head + sigmoid.
// Writes hi-fragments (blocked, 32 KB/block contiguous) to ghi for K1b, and A_hat.
// R12: struct head B restored to PARITY DOUBLE-BUFFER (bh/bl[2][2]) — the R1
// fused kernel ran this exact pattern at 128 VGPR no-spill, and k_embed holds
// LESS live state than R1's fused kernel. Previously B was loaded right before
// use -> ~200cy L2 latency exposed per ks step.
__global__ __launch_bounds__(256, 2) void k_embed(
    const int* __restrict__ q_seq, const int* __restrict__ r_seq,
    const float* __restrict__ t_seq, const float* __restrict__ q_tab,
    const float* __restrict__ r_tab,
    const ushort_t* __restrict__ ws1h, const ushort_t* __restrict__ ws1l,
    const float* __restrict__ consth, const float* __restrict__ Ws2,
    const float* __restrict__ bs2, const float* __restrict__ mask,
    float* __restrict__ out_ahat, ushort_t* __restrict__ ghi) {
    __shared__ __align__(16) ushort_t sAhi[16384];   // 64 pos x 256 k (hi), 32 KB
    __shared__ __align__(16) ushort_t sAlo[8192];    // 64 pos x 128 k (lo half), 16 KB
    __shared__ float sdiv[128];
    __shared__ float sLogit[64];
    int tid = threadIdx.x;
    if (tid < 128) sdiv[tid] = __expf((float)tid * -0.07195578415606394f); // -ln(10000)/128
    if (tid < 64) sLogit[tid] = 0.0f;
    int w = tid >> 6, lane = tid & 63;
    int pl = lane & 15, kq = lane >> 4;
    int nl = pl;
    int p0 = blockIdx.x * 64;
    int p = p0 + w * 16 + pl;
    int qv = q_seq[p];          // lanes with same pl share qv (same p)
    int rr = r_seq[p];
    float tt = t_seq[p];
    const float* grow = q_tab + (size_t)qv * 256;
    const float* rrow = r_tab + (size_t)rr * 256;
    uint4* gdst = (uint4*)(ghi + (size_t)blockIdx.x * 16384);
    __syncthreads();  // sdiv + sLogit ready
    // ---- gather + trig -> fragments to LDS (MFMA A-layout) + hi copy to global
    uint4 lo_hold[4];
#pragma unroll
    for (int it = 0; it < 8; ++it) {
        int kc = it * 4 + kq;
        int k0 = kc * 8;
        float4 qa = *(const float4*)(grow + kc * 8);
        float4 qb = *(const float4*)(grow + kc * 8 + 4);
        float4 ra = *(const float4*)(rrow + kc * 8);
        float4 rb = *(const float4*)(rrow + kc * 8 + 4);
        float v[8] = {qa.x + ra.x, qa.y + ra.y, qa.z + ra.z, qa.w + ra.w,
                      qb.x + rb.x, qb.y + rb.y, qb.z + rb.z, qb.w + rb.w};
        bool iscos = (kc >= 16);
#pragma unroll
        for (int j = 0; j < 8; ++j) {
            float ang = tt * sdiv[(k0 + j) & 127];
            v[j] += iscos ? __cosf(ang) : __sinf(ang);
        }
        ushort_t hs[8], ls[8];
#pragma unroll
        for (int j = 0; j < 8; ++j) {
            ushort_t h = f2bf(v[j]);
            hs[j] = h;
            ls[j] = (ushort_t)(__float_as_uint(v[j] - bf2f(h)) >> 16);
        }
        uint4 hv, lv;
        hv.x = hs[0] | ((uint_t)hs[1] << 16); hv.y = hs[2] | ((uint_t)hs[3] << 16);
        hv.z = hs[4] | ((uint_t)hs[5] << 16); hv.w = hs[6] | ((uint_t)hs[7] << 16);
        lv.x = ls[0] | ((uint_t)ls[1] << 16); lv.y = ls[2] | ((uint_t)ls[3] << 16);
        lv.z = ls[4] | ((uint_t)ls[5] << 16); lv.w = ls[6] | ((uint_t)ls[7] << 16);
        int unit = (w * 32 + kc) * 16 + pl;
        *(uint4*)(sAhi + unit * 8) = hv;
        gdst[unit] = hv;
        if (it < 4) {
            *(uint4*)(sAlo + ((w * 16 + kc) * 16 + pl) * 8) = lv;   // kc in 0..15
        } else {
            lo_hold[it - 4] = lv;
        }
    }
    __syncthreads();  // fragments visible block-wide
    // ---- struct head (split-bf16, 3 MFMAs), two k-phases over the halved sAlo,
    //      B parity-double-buffered (R1-verified pattern)
    {
        f32x4 acc[4][2];
        f32x4 z4 = {0.f, 0.f, 0.f, 0.f};
#pragma unroll
        for (int mt = 0; mt < 4; ++mt)
#pragma unroll
            for (int nt = 0; nt < 2; ++nt) acc[mt][nt] = z4;
        bf16x8 bh[2][2], bl[2][2];
#pragma unroll
        for (int nt = 0; nt < 2; ++nt) {
            int off = (((w * 2 + nt) * 32 + kq) * 16 + nl) * 8;
            bh[0][nt] = *(const bf16x8*)(ws1h + off);
            bl[0][nt] = *(const bf16x8*)(ws1l + off);
        }
#pragma unroll
        for (int ks = 0; ks < 8; ++ks) {
            if (ks == 4) {
                // swap in the second lo half (barrier: all phase-A sAlo reads done)
                __syncthreads();
#pragma unroll
                for (int it = 4; it < 8; ++it) {
                    int kc = it * 4 + kq;
                    *(uint4*)(sAlo + ((w * 16 + (kc - 16)) * 16 + pl) * 8) = lo_hold[it - 4];
                }
                __syncthreads();
            }
            int cur = ks & 1, nxt = cur ^ 1;
            if (ks < 7) {
#pragma unroll
                for (int nt = 0; nt < 2; ++nt) {
                    int off = (((w * 2 + nt) * 32 + (ks + 1) * 4 + kq) * 16 + nl) * 8;
                    bh[nxt][nt] = *(const bf16x8*)(ws1h + off);
                    bl[nxt][nt] = *(const bf16x8*)(ws1l + off);
                }
            }
            bf16x8 ahi[4], alo[4];
#pragma unroll
            for (int mt = 0; mt < 4; ++mt) {
                ahi[mt] = *(const bf16x8*)&sAhi[((mt * 32 + ks * 4 + kq) * 16 + nl) * 8];
                alo[mt] = *(const bf16x8*)&sAlo[((mt * 16 + (ks & 3) * 4 + kq) * 16 + nl) * 8];
            }
#pragma unroll
            for (int mt = 0; mt < 4; ++mt)
#pragma unroll
                for (int nt = 0; nt < 2; ++nt) {
                    acc[mt][nt] = MFMA16(ahi[mt], bh[cur][nt], acc[mt][nt]);
                    acc[mt][nt] = MFMA16(alo[mt], bh[cur][nt], acc[mt][nt]);
                    acc[mt][nt] = MFMA16(ahi[mt], bl[cur][nt], acc[mt][nt]);
                }
        }
        // epilogue: hdn = leaky(acc + const_h); partial logits = hdn * Ws2
        float ps[4][4];
#pragma unroll
        for (int mt = 0; mt < 4; ++mt)
#pragma unroll
            for (int r = 0; r < 4; ++r) ps[mt][r] = 0.f;
#pragma unroll
        for (int nt = 0; nt < 2; ++nt) {
            int ng = w * 32 + nt * 16 + nl;
            float chv = consth[ng], w2 = Ws2[ng];
#pragma unroll
            for (int mt = 0; mt < 4; ++mt)
#pragma unroll
                for (int r = 0; r < 4; ++r) {
                    float v = acc[mt][nt][r] + chv;
                    v = fmaxf(v, 0.2f * v);
                    ps[mt][r] += v * w2;
                }
        }
#pragma unroll
        for (int mt = 0; mt < 4; ++mt)
#pragma unroll
            for (int r = 0; r < 4; ++r) {
                float x = ps[mt][r];
                x += __shfl_xor(x, 1, 64);
                x += __shfl_xor(x, 2, 64);
                x += __shfl_xor(x, 4, 64);
                x += __shfl_xor(x, 8, 64);
                ps[mt][r] = x;
            }
        if (nl == 0) {
#pragma unroll
            for (int mt = 0; mt < 4; ++mt)
#pragma unroll
                for (int r = 0; r < 4; ++r)
                    atomicAdd(&sLogit[mt * 16 + kq * 4 + r], ps[mt][r]);
        }
    }
    __syncthreads();
    if (tid < 64) {
        int pp = p0 + tid;
        float lg = sLogit[tid] + bs2[0];
        float y = lg * 100.0f;
        y = fminf(fmaxf(y, -60.f), 60.f);
        float a = 1.0f / (1.0f + expf(-y));
        out_ahat[pp] = a * mask[pp];
    }
}

// ---------------- K1b: Wa GEMM + aggregator — R4-EXACT (verified 88.6 µs,
// 112 VGPR, no spill). Six structural variants (prefetch depth, LDS-free,
// min-waves=3, M=128, inverted tile) all nulled/spilled/regressed: this is
// the pinned optimum for this allocator. 64 pos/block, grid 2048.
__global__ __launch_bounds__(256, 2) void k_wa(
    const ushort_t* __restrict__ ghi, const float* __restrict__ out_ahat,
    const ushort_t* __restrict__ wa_b, const float* __restrict__ ba,
    float* __restrict__ u_i) {
    __shared__ __align__(16) ushort_t sA[16384];   // 64 pos x 256 k (hi), 32 KB
    __shared__ float sAh[64];
    int tid = threadIdx.x;
    int p0 = blockIdx.x * 64;
    // stage A-tile: 32 KB contiguous
    {
        const uint4* src = (const uint4*)(ghi + (size_t)blockIdx.x * 16384);
        uint4* dst = (uint4*)sA;
#pragma unroll
        for (int i = 0; i < 8; ++i) dst[tid + i * 256] = src[tid + i * 256];
    }
    if (tid < 64) sAh[tid] = out_ahat[p0 + tid];
    __syncthreads();
    int w = tid >> 6, lane = tid & 63;
    int pl = lane & 15, kq = lane >> 4;
    int nl = pl;
    float ah[16];
#pragma unroll
    for (int mt = 0; mt < 4; ++mt)
#pragma unroll
        for (int r = 0; r < 4; ++r) ah[mt * 4 + r] = sAh[mt * 16 + kq * 4 + r];
    int bidx = p0 >> 11;   // sequence index (2048 positions per sequence)
#pragma unroll 1
    for (int nblk = 0; nblk < 4; ++nblk) {
#pragma unroll 1
        for (int hf = 0; hf < 2; ++hf) {
            const ushort_t* gB = wa_b + (size_t)(w * 16 + nblk * 4 + hf * 2) * 4096 + lane * 8;
            f32x4 acc[4][2];
            bf16x8 bfr[2][2];
#pragma unroll
            for (int nt = 0; nt < 2; ++nt)
                bfr[0][nt] = *(const bf16x8*)(gB + nt * 4096);
#pragma unroll
            for (int ks = 0; ks < 8; ++ks) {
                int cur = ks & 1, nxt = cur ^ 1;
                if (ks < 7) {
#pragma unroll
                    for (int nt = 0; nt < 2; ++nt)
                        bfr[nxt][nt] = *(const bf16x8*)(gB + nt * 4096 + (ks + 1) * 512);
                }
                bf16x8 a_[4];
#pragma unroll
                for (int mt = 0; mt < 4; ++mt)
                    a_[mt] = *(const bf16x8*)&sA[((mt * 32 + ks * 4 + kq) * 16 + nl) * 8];
                if (ks == 0) {
                    f32x4 z4 = {0.f, 0.f, 0.f, 0.f};
#pragma unroll
                    for (int mt = 0; mt < 4; ++mt)
#pragma unroll
                        for (int nt = 0; nt < 2; ++nt)
                            acc[mt][nt] = MFMA16(a_[mt], bfr[0][nt], z4);
                } else {
#pragma unroll
                    for (int mt = 0; mt < 4; ++mt)
#pragma unroll
                        for (int nt = 0; nt < 2; ++nt)
                            acc[mt][nt] = MFMA16(a_[mt], bfr[cur][nt], acc[mt][nt]);
                }
            }
            // epilogue: leaky(acc+ba)*A_hat, reduce the 64 m-rows, atomicAdd u_i
#pragma unroll
            for (int nt = 0; nt < 2; ++nt) {
                int ng = w * 256 + nblk * 64 + (hf * 2 + nt) * 16 + nl;
                float ban = ba[ng];
                float s = 0.f;
#pragma unroll
                for (int mt = 0; mt < 4; ++mt)
#pragma unroll
                    for (int r = 0; r < 4; ++r) {
                        float v = acc[mt][nt][r] + ban;
                        v = fmaxf(v, 0.2f * v);
                        s += v * ah[mt * 4 + r];
                    }
                s += __shfl_xor(s, 16, 64);
                s += __shfl_xor(s, 32, 64);
                if (kq == 0) atomicAdd(&u_i[bidx * 1024 + ng], s);
            }
        }
    }
}

// ---------------- Fallback: the verified R1 fully-fused kernel (used only if
// the workspace is too small for ghi).
__global__ __launch_bounds__(256, 2) void k_fused_fb(
    const int* __restrict__ q_seq, const int* __restrict__ r_seq,
    const float* __restrict__ t_seq, const float* __restrict__ q_tab,
    const float* __restrict__ r_tab,
    const ushort_t* __restrict__ ws1h, const ushort_t* __restrict__ ws1l,
    const float* __restrict__ consth, const float* __restrict__ Ws2,
    const float* __restrict__ bs2, const float* __restrict__ mask,
    const ushort_t* __restrict__ wa_b, const float* __restrict__ ba,
    float* __restrict__ out_ahat, float* __restrict__ u_i) {
    __shared__ __align__(16) ushort_t sAhi[16384];
    __shared__ __align__(16) ushort_t sAlo[16384];
    __shared__ float sdiv[128];
    __shared__ float sLogit[64];
    __shared__ float sAh[64];
    int tid = threadIdx.x;
    if (tid < 128) sdiv[tid] = __expf((float)tid * -0.07195578415606394f);
    if (tid < 64) sLogit[tid] = 0.0f;
    int w = tid >> 6, lane = tid & 63;
    int pl = lane & 15, kq = lane >> 4;
    int nl = pl;
    int p0 = blockIdx.x * 64;
    int p = p0 + w * 16 + pl;
    int qv = q_seq[p];
    int rr = r_seq[p];
    float tt = t_seq[p];
    const float* grow = q_tab + (size_t)qv * 256;
    const float* rrow = r_tab + (size_t)rr * 256;
    __syncthreads();
#pragma unroll
    for (int it = 0; it < 8; ++it) {
        int kc = it * 4 + kq;
        int k0 = kc * 8;
        float4 qa = *(const float4*)(grow + kc * 8);
        float4 qb = *(const float4*)(grow + kc * 8 + 4);
        float4 ra = *(const float4*)(rrow + kc * 8);
        float4 rb = *(const float4*)(rrow + kc * 8 + 4);
        float v[8] = {qa.x + ra.x, qa.y + ra.y, qa.z + ra.z, qa.w + ra.w,
                      qb.x + rb.x, qb.y + rb.y, qb.z + rb.z, qb.w + rb.w};
        bool iscos = (kc >= 16);
#pragma unroll
        for (int j = 0; j < 8; ++j) {
            float ang = tt * sdiv[(k0 + j) & 127];
            v[j] += iscos ? __cosf(ang) : __sinf(ang);
        }
        ushort_t hs[8], ls[8];
#pragma unroll
        for (int j = 0; j < 8; ++j) {
            ushort_t h = f2bf(v[j]);
            hs[j] = h;
            ls[j] = (ushort_t)(__float_as_uint(v[j] - bf2f(h)) >> 16);
        }
        uint4 hv, lv;
        hv.x = hs[0] | ((uint_t)hs[1] << 16); hv.y = hs[2] | ((uint_t)hs[3] << 16);
        hv.z = hs[4] | ((uint_t)hs[5] << 16); hv.w = hs[6] | ((uint_t)hs[7] << 16);
        lv.x = ls[0] | ((uint_t)ls[1] << 16); lv.y = ls[2] | ((uint_t)ls[3] << 16);
        lv.z = ls[4] | ((uint_t)ls[5] << 16); lv.w = ls[6] | ((uint_t)ls[7] << 16);
        int loff = ((w * 32 + kc) * 16 + pl) * 8;
        *(uint4*)(sAhi + loff) = hv;
        *(uint4*)(sAlo + loff) = lv;
    }
    __syncthreads();
    {
        f32x4 acc[4][2];
        f32x4 z4 = {0.f, 0.f, 0.f, 0.f};
#pragma unroll
        for (int mt = 0; mt < 4; ++mt)
#pragma unroll
            for (int nt = 0; nt < 2; ++nt) acc[mt][nt] = z4;
        bf16x8 bh[2][2], bl[2][2];
#pragma unroll
        for (int nt = 0; nt < 2; ++nt) {
            int off = (((w * 2 + nt) * 32 + kq) * 16 + nl) * 8;
            bh[0][nt] = *(const bf16x8*)(ws1h + off);
            bl[0][nt] = *(const bf16x8*)(ws1l + off);
        }
#pragma unroll
        for (int ks = 0; ks < 8; ++ks) {
            int cur = ks & 1, nxt = cur ^ 1;
            if (ks < 7) {
#pragma unroll
                for (int nt = 0; nt < 2; ++nt) {
                    int off = (((w * 2 + nt) * 32 + (ks + 1) * 4 + kq) * 16 + nl) * 8;
                    bh[nxt][nt] = *(const bf16x8*)(ws1h + off);
                    bl[nxt][nt] = *(const bf16x8*)(ws1l + off);
                }
            }
            bf16x8 ahi[4], alo[4];
#pragma unroll
            for (int mt = 0; mt < 4; ++mt) {
                int off = ((mt * 32 + ks * 4 + kq) * 16 + nl) * 8;
                ahi[mt] = *(const bf16x8*)&sAhi[off];
                alo[mt] = *(const bf16x8*)&sAlo[off];
            }
#pragma unroll
            for (int mt = 0; mt < 4; ++mt)
#pragma unroll
                for (int nt = 0; nt < 2; ++nt) {
                    acc[mt][nt] = MFMA16(ahi[mt], bh[cur][nt], acc[mt][nt]);
                    acc[mt][nt] = MFMA16(alo[mt], bh[cur][nt], acc[mt][nt]);
                    acc[mt][nt] = MFMA16(ahi[mt], bl[cur][nt], acc[mt][nt]);
                }
        }
        float ps[4][4];
#pragma unroll
        for (int mt = 0; mt < 4; ++mt)
#pragma unroll
            for (int r = 0; r < 4; ++r) ps[mt][r] = 0.f;
#pragma unroll
        for (int nt = 0; nt < 2; ++nt) {
            int ng = w * 32 + nt * 16 + nl;
            float chv = consth[ng], w2 = Ws2[ng];
#pragma unroll
            for (int mt = 0; mt < 4; ++mt)
#pragma unroll
                for (int r = 0; r < 4; ++r) {
                    float v = acc[mt][nt][r] + chv;
                    v = fmaxf(v, 0.2f * v);
                    ps[mt][r] += v * w2;
                }
        }
#pragma unroll
        for (int mt = 0; mt < 4; ++mt)
#pragma unroll
            for (int r = 0; r < 4; ++r) {
                float x = ps[mt][r];
                x += __shfl_xor(x, 1, 64);
                x += __shfl_xor(x, 2, 64);
                x += __shfl_xor(x, 4, 64);
                x += __shfl_xor(x, 8, 64);
                ps[mt][r] = x;
            }
        if (nl == 0) {
#pragma unroll
            for (int mt = 0; mt < 4; ++mt)
#pragma unroll
                for (int r = 0; r < 4; ++r)
                    atomicAdd(&sLogit[mt * 16 + kq * 4 + r], ps[mt][r]);
        }
    }
    __syncthreads();
    if (tid < 64) {
        int pp = p0 + tid;
        float lg = sLogit[tid] + bs2[0];
        float y = lg * 100.0f;
        y = fminf(fmaxf(y, -60.f), 60.f);
        float a = 1.0f / (1.0f + expf(-y));
        float av = a * mask[pp];
        out_ahat[pp] = av;
        sAh[tid] = av;
    }
    __syncthreads();
    {
        float ah[16];
#pragma unroll
        for (int mt = 0; mt < 4; ++mt)
#pragma unroll
            for (int r = 0; r < 4; ++r) ah[mt * 4 + r] = sAh[mt * 16 + kq * 4 + r];
        int bidx = p0 >> 11;
#pragma unroll 1
        for (int nblk = 0; nblk < 4; ++nblk) {
#pragma unroll 1
            for (int hf = 0; hf < 2; ++hf) {
                const ushort_t* gB = wa_b + (size_t)(w * 16 + nblk * 4 + hf * 2) * 4096 + lane * 8;
                f32x4 acc[4][2];
                bf16x8 bfr[2][2];
#pragma unroll
                for (int nt = 0; nt < 2; ++nt)
                    bfr[0][nt] = *(const bf16x8*)(gB + nt * 4096);
#pragma unroll
                for (int ks = 0; ks < 8; ++ks) {
                    int cur = ks & 1, nxt = cur ^ 1;
                    if (ks < 7) {
#pragma unroll
                        for (int nt = 0; nt < 2; ++nt)
                            bfr[nxt][nt] = *(const bf16x8*)(gB + nt * 4096 + (ks + 1) * 512);
                    }
                    bf16x8 a_[4];
#pragma unroll
                    for (int mt = 0; mt < 4; ++mt)
                        a_[mt] = *(const bf16x8*)&sAhi[((mt * 32 + ks * 4 + kq) * 16 + nl) * 8];
                    if (ks == 0) {
                        f32x4 z4 = {0.f, 0.f, 0.f, 0.f};
#pragma unroll
                        for (int mt = 0; mt < 4; ++mt)
#pragma unroll
                            for (int nt = 0; nt < 2; ++nt)
                                acc[mt][nt] = MFMA16(a_[mt], bfr[0][nt], z4);
                    } else {
#pragma unroll
                        for (int mt = 0; mt < 4; ++mt)
#pragma unroll
                            for (int nt = 0; nt < 2; ++nt)
                                acc[mt][nt] = MFMA16(a_[mt], bfr[cur][nt], acc[mt][nt]);
                    }
                }
#pragma unroll
                for (int nt = 0; nt < 2; ++nt) {
                    int ng = w * 256 + nblk * 64 + (hf * 2 + nt) * 16 + nl;
                    float ban = ba[ng];
                    float s = 0.f;
#pragma unroll
                    for (int mt = 0; mt < 4; ++mt)
#pragma unroll
                        for (int r = 0; r < 4; ++r) {
                            float v = acc[mt][nt][r] + ban;
                            v = fmaxf(v, 0.2f * v);
                            s += v * ah[mt * 4 + r];
                        }
                    s += __shfl_xor(s, 16, 64);
                    s += __shfl_xor(s, 32, 64);
                    if (kq == 0) atomicAdd(&u_i[bidx * 1024 + ng], s);
                }
            }
        }
    }
}

extern "C" void kernel_launch(void* const* d_in, const int* in_sizes, int n_in,
                              void* d_out, int out_size, void* d_ws, size_t ws_size,
                              hipStream_t stream) {
    const int* q_seq = (const int*)d_in[0];
    const int* r_seq = (const int*)d_in[1];
    const float* t_seq = (const float*)d_in[2];
    const float* mask = (const float*)d_in[3];
    const float* q_tab = (const float*)d_in[4];
    const float* r_tab = (const float*)d_in[5];
    const float* virt = (const float*)d_in[6];
    const float* Ws1 = (const float*)d_in[7];
    const float* bs1 = (const float*)d_in[8];
    const float* Ws2 = (const float*)d_in[9];
    const float* bs2 = (const float*)d_in[10];
    const float* Wa = (const float*)d_in[11];
    const float* ba = (const float*)d_in[12];
    float* out = (float*)d_out;

    // ws layout
    ushort_t* wa_b = (ushort_t*)d_ws;            // 1024*256 bf16 blocked (512 KB)
    ushort_t* ws1h = wa_b + 262144;              // 128*256 bf16 blocked (64 KB)
    ushort_t* ws1l = ws1h + 32768;               // 64 KB
    float* ch = (float*)(ws1l + 32768);          // 128 f32 (512 B)
    ushort_t* ghi = (ushort_t*)(ch + 128);       // 131072*256 bf16 blocked (64 MB)
    const size_t need = 524288 + 65536 + 65536 + 512 + 67108864;

    hipLaunchKernelGGL(k_prep, dim3(216), dim3(256), 0, stream,
                       Ws1, bs1, virt, Wa, ch, wa_b, ws1h, ws1l, out);
    if (ws_size >= need) {
        hipLaunchKernelGGL(k_embed, dim3(2048), dim3(256), 0, stream,
                           q_seq, r_seq, t_seq, q_tab, r_tab, ws1h, ws1l, ch, Ws2,
                           bs2, mask, out + 65536, ghi);
        hipLaunchKernelGGL(k_wa, dim3(2048), dim3(256), 0, stream,
                           ghi, out + 65536, wa_b, ba, out);
    } else {
        hipLaunchKernelGGL(k_fused_fb, dim3(2048), dim3(256), 0, stream,
                           q_seq, r_seq, t_seq, q_tab, r_tab, ws1h, ws1l, ch, Ws2,
                           bs2, mask, wa_b, ba, out + 65536, out);
    }
}

// Round 13
// 239.156 us; speedup vs baseline: 1.2095x; 1.0130x over previous
//
#include <hip/hip_runtime.h>

typedef unsigned short ushort_t;
typedef unsigned int uint_t;

typedef short bf16x8 __attribute__((ext_vector_type(8)));
typedef float f32x4 __attribute__((ext_vector_type(4)));

#define MFMA16(a, b, c) __builtin_amdgcn_mfma_f32_16x16x32_bf16(a, b, c, 0, 0, 0)

__device__ __forceinline__ ushort_t f2bf(float f) {
    uint_t u = __float_as_uint(f);
    u += 0x7fffu + ((u >> 16) & 1u);   // RNE
    return (ushort_t)(u >> 16);
}
__device__ __forceinline__ float bf2f(ushort_t h) {
    return __uint_as_float(((uint_t)h) << 16);
}

// ---------------- K0: fused prep (R10 version — verified best).
// blocks 0..7: const_h wave-parallel; 8..135: Wa->bf16 blocked;
// 136..151: Ws1[:, :256] -> bf16 hi/lo blocked; 152..215: zero u_i.
// blocked flat (in 8-elem units): ((row/16)*32 + k/8)*16 + row%16
__global__ void k_prep(const float* __restrict__ Ws1, const float* __restrict__ bs1,
                       const float* __restrict__ virt, const float* __restrict__ Wa,
                       float* __restrict__ consth, ushort_t* __restrict__ wa_b,
                       ushort_t* __restrict__ ws1h, ushort_t* __restrict__ ws1l,
                       float* __restrict__ u_i) {
    int b = blockIdx.x;
    if (b < 8) {
        int w = threadIdx.x >> 6, lane = threadIdx.x & 63;
#pragma unroll
        for (int i = 0; i < 4; ++i) {
            int row = b * 16 + w * 4 + i;
            const float* rp = Ws1 + row * 512 + 256;
            float4 v = *(const float4*)(rp + lane * 4);
            float4 vv = *(const float4*)(virt + lane * 4);
            float s = v.x * vv.x + v.y * vv.y + v.z * vv.z + v.w * vv.w;
            s += __shfl_xor(s, 1, 64);
            s += __shfl_xor(s, 2, 64);
            s += __shfl_xor(s, 4, 64);
            s += __shfl_xor(s, 8, 64);
            s += __shfl_xor(s, 16, 64);
            s += __shfl_xor(s, 32, 64);
            if (lane == 0) consth[row] = bs1[row] + s;
        }
        return;
    }
    if (b >= 152) {
        int t = (b - 152) * 1024 + threadIdx.x * 4;
        float4 z = {0.f, 0.f, 0.f, 0.f};
        *(float4*)(u_i + t) = z;
        return;
    }
    const float* src;
    int src_stride, tid;
    ushort_t *dhi, *dlo;
    if (b <= 135) {
        tid = (b - 8) * 256 + threadIdx.x;   // 1024 rows * 32 = 32768 tids
        src = Wa; src_stride = 256; dhi = wa_b; dlo = nullptr;
    } else {
        tid = (b - 136) * 256 + threadIdx.x; // 128 rows * 32 = 4096 tids
        src = Ws1; src_stride = 512; dhi = ws1h; dlo = ws1l;
    }
    int pl = tid & 15, kc = (tid >> 4) & 31, pt = tid >> 9;
    int row = pt * 16 + pl;
    const float* s = src + (size_t)row * src_stride + kc * 8;
    ushort_t hs[8], ls[8];
#pragma unroll
    for (int j = 0; j < 8; ++j) {
        float v = s[j];
        ushort_t h = f2bf(v);
        hs[j] = h;
        ls[j] = f2bf(v - bf2f(h));
    }
    uint4 hv;
    hv.x = hs[0] | ((uint_t)hs[1] << 16); hv.y = hs[2] | ((uint_t)hs[3] << 16);
    hv.z = hs[4] | ((uint_t)hs[5] << 16); hv.w = hs[6] | ((uint_t)hs[7] << 16);
    *(uint4*)(dhi + (size_t)tid * 8) = hv;
    if (dlo) {
        uint4 lv;
        lv.x = ls[0] | ((uint_t)ls[1] << 16); lv.y = ls[2] | ((uint_t)ls[3] << 16);
        lv.z = ls[4] | ((uint_t)ls[5] << 16); lv.w = ls[6] | ((uint_t)ls[7] << 16);
        *(uint4*)(dlo + (size_t)tid * 8) = lv;
    }
}

// ---------------- K1a: embed (gather+trig) + split-bf16 struct head + sigmoid.
// Writes hi-fragments (blocked, 32 KB/block contiguous) to ghi for K1b, and A_hat.
// R4-exact (verified in the 240.5 µs best run; R12's B-dbuf variant was null
// within noise and is reverted).
__global__ __launch_bounds__(256, 2) void k_embed(
    const int* __restrict__ q_seq, const int* __restrict__ r_seq,
    const float* __restrict__ t_seq, const float* __restrict__ q_tab,
    const float* __restrict__ r_tab,
    const ushort_t* __restrict__ ws1h, const ushort_t* __restrict__ ws1l,
    const float* __restrict__ consth, const float* __restrict__ Ws2,
    const float* __restrict__ bs2, const float* __restrict__ mask,
    float* __restrict__ out_ahat, ushort_t* __restrict__ ghi) {
    __shared__ __align__(16) ushort_t sAhi[16384];   // 64 pos x 256 k (hi), 32 KB
    __shared__ __align__(16) ushort_t sAlo[8192];    // 64 pos x 128 k (lo half), 16 KB
    __shared__ float sdiv[128];
    __shared__ float sLogit[64];
    int tid = threadIdx.x;
    if (tid < 128) sdiv[tid] = __expf((float)tid * -0.07195578415606394f); // -ln(10000)/128
    if (tid < 64) sLogit[tid] = 0.0f;
    int w = tid >> 6, lane = tid & 63;
    int pl = lane & 15, kq = lane >> 4;
    int nl = pl;
    int p0 = blockIdx.x * 64;
    int p = p0 + w * 16 + pl;
    int qv = q_seq[p];          // lanes with same pl share qv (same p)
    int rr = r_seq[p];
    float tt = t_seq[p];
    const float* grow = q_tab + (size_t)qv * 256;
    const float* rrow = r_tab + (size_t)rr * 256;
    uint4* gdst = (uint4*)(ghi + (size_t)blockIdx.x * 16384);
    __syncthreads();  // sdiv + sLogit ready
    // ---- gather + trig -> fragments to LDS (MFMA A-layout) + hi copy to global
    uint4 lo_hold[4];
#pragma unroll
    for (int it = 0; it < 8; ++it) {
        int kc = it * 4 + kq;
        int k0 = kc * 8;
        float4 qa = *(const float4*)(grow + kc * 8);
        float4 qb = *(const float4*)(grow + kc * 8 + 4);
        float4 ra = *(const float4*)(rrow + kc * 8);
        float4 rb = *(const float4*)(rrow + kc * 8 + 4);
        float v[8] = {qa.x + ra.x, qa.y + ra.y, qa.z + ra.z, qa.w + ra.w,
                      qb.x + rb.x, qb.y + rb.y, qb.z + rb.z, qb.w + rb.w};
        bool iscos = (kc >= 16);
#pragma unroll
        for (int j = 0; j < 8; ++j) {
            float ang = tt * sdiv[(k0 + j) & 127];
            v[j] += iscos ? __cosf(ang) : __sinf(ang);
        }
        ushort_t hs[8], ls[8];
#pragma unroll
        for (int j = 0; j < 8; ++j) {
            ushort_t h = f2bf(v[j]);
            hs[j] = h;
            ls[j] = (ushort_t)(__float_as_uint(v[j] - bf2f(h)) >> 16);
        }
        uint4 hv, lv;
        hv.x = hs[0] | ((uint_t)hs[1] << 16); hv.y = hs[2] | ((uint_t)hs[3] << 16);
        hv.z = hs[4] | ((uint_t)hs[5] << 16); hv.w = hs[6] | ((uint_t)hs[7] << 16);
        lv.x = ls[0] | ((uint_t)ls[1] << 16); lv.y = ls[2] | ((uint_t)ls[3] << 16);
        lv.z = ls[4] | ((uint_t)ls[5] << 16); lv.w = ls[6] | ((uint_t)ls[7] << 16);
        int unit = (w * 32 + kc) * 16 + pl;
        *(uint4*)(sAhi + unit * 8) = hv;
        gdst[unit] = hv;
        if (it < 4) {
            *(uint4*)(sAlo + ((w * 16 + kc) * 16 + pl) * 8) = lv;   // kc in 0..15
        } else {
            lo_hold[it - 4] = lv;
        }
    }
    __syncthreads();  // fragments visible block-wide
    // ---- struct head (split-bf16, 3 MFMAs), two k-phases over the halved sAlo
    {
        f32x4 acc[4][2];
        f32x4 z4 = {0.f, 0.f, 0.f, 0.f};
#pragma unroll
        for (int mt = 0; mt < 4; ++mt)
#pragma unroll
            for (int nt = 0; nt < 2; ++nt) acc[mt][nt] = z4;
#pragma unroll
        for (int ks = 0; ks < 8; ++ks) {
            if (ks == 4) {
                // swap in the second lo half (barrier: all phase-A sAlo reads done)
                __syncthreads();
#pragma unroll
                for (int it = 4; it < 8; ++it) {
                    int kc = it * 4 + kq;
                    *(uint4*)(sAlo + ((w * 16 + (kc - 16)) * 16 + pl) * 8) = lo_hold[it - 4];
                }
                __syncthreads();
            }
            bf16x8 bh[2], bl[2];
#pragma unroll
            for (int nt = 0; nt < 2; ++nt) {
                int off = (((w * 2 + nt) * 32 + ks * 4 + kq) * 16 + nl) * 8;
                bh[nt] = *(const bf16x8*)(ws1h + off);
                bl[nt] = *(const bf16x8*)(ws1l + off);
            }
#pragma unroll
            for (int mth = 0; mth < 2; ++mth) {
                bf16x8 ahi[2], alo[2];
#pragma unroll
                for (int mi = 0; mi < 2; ++mi) {
                    int mt = mth * 2 + mi;
                    ahi[mi] = *(const bf16x8*)&sAhi[((mt * 32 + ks * 4 + kq) * 16 + nl) * 8];
                    alo[mi] = *(const bf16x8*)&sAlo[((mt * 16 + (ks & 3) * 4 + kq) * 16 + nl) * 8];
                }
#pragma unroll
                for (int mi = 0; mi < 2; ++mi)
#pragma unroll
                    for (int nt = 0; nt < 2; ++nt) {
                        int mt = mth * 2 + mi;
                        acc[mt][nt] = MFMA16(ahi[mi], bh[nt], acc[mt][nt]);
                        acc[mt][nt] = MFMA16(alo[mi], bh[nt], acc[mt][nt]);
                        acc[mt][nt] = MFMA16(ahi[mi], bl[nt], acc[mt][nt]);
                    }
            }
        }
        // epilogue: hdn = leaky(acc + const_h); partial logits = hdn * Ws2
        float ps[4][4];
#pragma unroll
        for (int mt = 0; mt < 4; ++mt)
#pragma unroll
            for (int r = 0; r < 4; ++r) ps[mt][r] = 0.f;
#pragma unroll
        for (int nt = 0; nt < 2; ++nt) {
            int ng = w * 32 + nt * 16 + nl;
            float chv = consth[ng], w2 = Ws2[ng];
#pragma unroll
            for (int mt = 0; mt < 4; ++mt)
#pragma unroll
                for (int r = 0; r < 4; ++r) {
                    float v = acc[mt][nt][r] + chv;
                    v = fmaxf(v, 0.2f * v);
                    ps[mt][r] += v * w2;
                }
        }
#pragma unroll
        for (int mt = 0; mt < 4; ++mt)
#pragma unroll
            for (int r = 0; r < 4; ++r) {
                float x = ps[mt][r];
                x += __shfl_xor(x, 1, 64);
                x += __shfl_xor(x, 2, 64);
                x += __shfl_xor(x, 4, 64);
                x += __shfl_xor(x, 8, 64);
                ps[mt][r] = x;
            }
        if (nl == 0) {
#pragma unroll
            for (int mt = 0; mt < 4; ++mt)
#pragma unroll
                for (int r = 0; r < 4; ++r)
                    atomicAdd(&sLogit[mt * 16 + kq * 4 + r], ps[mt][r]);
        }
    }
    __syncthreads();
    if (tid < 64) {
        int pp = p0 + tid;
        float lg = sLogit[tid] + bs2[0];
        float y = lg * 100.0f;
        y = fminf(fmaxf(y, -60.f), 60.f);
        float a = 1.0f / (1.0f + expf(-y));
        out_ahat[pp] = a * mask[pp];
    }
}

// ---------------- K1b: Wa GEMM + aggregator — R4-EXACT (verified 88.6 µs,
// 112 VGPR, no spill). Six structural variants (prefetch depth, LDS-free,
// min-waves=3, M=128, inverted tile) all nulled/spilled/regressed: this is
// the pinned optimum for this allocator. 64 pos/block, grid 2048.
__global__ __launch_bounds__(256, 2) void k_wa(
    const ushort_t* __restrict__ ghi, const float* __restrict__ out_ahat,
    const ushort_t* __restrict__ wa_b, const float* __restrict__ ba,
    float* __restrict__ u_i) {
    __shared__ __align__(16) ushort_t sA[16384];   // 64 pos x 256 k (hi), 32 KB
    __shared__ float sAh[64];
    int tid = threadIdx.x;
    int p0 = blockIdx.x * 64;
    // stage A-tile: 32 KB contiguous
    {
        const uint4* src = (const uint4*)(ghi + (size_t)blockIdx.x * 16384);
        uint4* dst = (uint4*)sA;
#pragma unroll
        for (int i = 0; i < 8; ++i) dst[tid + i * 256] = src[tid + i * 256];
    }
    if (tid < 64) sAh[tid] = out_ahat[p0 + tid];
    __syncthreads();
    int w = tid >> 6, lane = tid & 63;
    int pl = lane & 15, kq = lane >> 4;
    int nl = pl;
    float ah[16];
#pragma unroll
    for (int mt = 0; mt < 4; ++mt)
#pragma unroll
        for (int r = 0; r < 4; ++r) ah[mt * 4 + r] = sAh[mt * 16 + kq * 4 + r];
    int bidx = p0 >> 11;   // sequence index (2048 positions per sequence)
#pragma unroll 1
    for (int nblk = 0; nblk < 4; ++nblk) {
#pragma unroll 1
        for (int hf = 0; hf < 2; ++hf) {
            const ushort_t* gB = wa_b + (size_t)(w * 16 + nblk * 4 + hf * 2) * 4096 + lane * 8;
            f32x4 acc[4][2];
            bf16x8 bfr[2][2];
#pragma unroll
            for (int nt = 0; nt < 2; ++nt)
                bfr[0][nt] = *(const bf16x8*)(gB + nt * 4096);
#pragma unroll
            for (int ks = 0; ks < 8; ++ks) {
                int cur = ks & 1, nxt = cur ^ 1;
                if (ks < 7) {
#pragma unroll
                    for (int nt = 0; nt < 2; ++nt)
                        bfr[nxt][nt] = *(const bf16x8*)(gB + nt * 4096 + (ks + 1) * 512);
                }
                bf16x8 a_[4];
#pragma unroll
                for (int mt = 0; mt < 4; ++mt)
                    a_[mt] = *(const bf16x8*)&sA[((mt * 32 + ks * 4 + kq) * 16 + nl) * 8];
                if (ks == 0) {
                    f32x4 z4 = {0.f, 0.f, 0.f, 0.f};
#pragma unroll
                    for (int mt = 0; mt < 4; ++mt)
#pragma unroll
                        for (int nt = 0; nt < 2; ++nt)
                            acc[mt][nt] = MFMA16(a_[mt], bfr[0][nt], z4);
                } else {
#pragma unroll
                    for (int mt = 0; mt < 4; ++mt)
#pragma unroll
                        for (int nt = 0; nt < 2; ++nt)
                            acc[mt][nt] = MFMA16(a_[mt], bfr[cur][nt], acc[mt][nt]);
                }
            }
            // epilogue: leaky(acc+ba)*A_hat, reduce the 64 m-rows, atomicAdd u_i
#pragma unroll
            for (int nt = 0; nt < 2; ++nt) {
                int ng = w * 256 + nblk * 64 + (hf * 2 + nt) * 16 + nl;
                float ban = ba[ng];
                float s = 0.f;
#pragma unroll
                for (int mt = 0; mt < 4; ++mt)
#pragma unroll
                    for (int r = 0; r < 4; ++r) {
                        float v = acc[mt][nt][r] + ban;
                        v = fmaxf(v, 0.2f * v);
                        s += v * ah[mt * 4 + r];
                    }
                s += __shfl_xor(s, 16, 64);
                s += __shfl_xor(s, 32, 64);
                if (kq == 0) atomicAdd(&u_i[bidx * 1024 + ng], s);
            }
        }
    }
}

// ---------------- Fallback: the verified R1 fully-fused kernel (used only if
// the workspace is too small for ghi).
__global__ __launch_bounds__(256, 2) void k_fused_fb(
    const int* __restrict__ q_seq, const int* __restrict__ r_seq,
    const float* __restrict__ t_seq, const float* __restrict__ q_tab,
    const float* __restrict__ r_tab,
    const ushort_t* __restrict__ ws1h, const ushort_t* __restrict__ ws1l,
    const float* __restrict__ consth, const float* __restrict__ Ws2,
    const float* __restrict__ bs2, const float* __restrict__ mask,
    const ushort_t* __restrict__ wa_b, const float* __restrict__ ba,
    float* __restrict__ out_ahat, float* __restrict__ u_i) {
    __shared__ __align__(16) ushort_t sAhi[16384];
    __shared__ __align__(16) ushort_t sAlo[16384];
    __shared__ float sdiv[128];
    __shared__ float sLogit[64];
    __shared__ float sAh[64];
    int tid = threadIdx.x;
    if (tid < 128) sdiv[tid] = __expf((float)tid * -0.07195578415606394f);
    if (tid < 64) sLogit[tid] = 0.0f;
    int w = tid >> 6, lane = tid & 63;
    int pl = lane & 15, kq = lane >> 4;
    int nl = pl;
    int p0 = blockIdx.x * 64;
    int p = p0 + w * 16 + pl;
    int qv = q_seq[p];
    int rr = r_seq[p];
    float tt = t_seq[p];
    const float* grow = q_tab + (size_t)qv * 256;
    const float* rrow = r_tab + (size_t)rr * 256;
    __syncthreads();
#pragma unroll
    for (int it = 0; it < 8; ++it) {
        int kc = it * 4 + kq;
        int k0 = kc * 8;
        float4 qa = *(const float4*)(grow + kc * 8);
        float4 qb = *(const float4*)(grow + kc * 8 + 4);
        float4 ra = *(const float4*)(rrow + kc * 8);
        float4 rb = *(const float4*)(rrow + kc * 8 + 4);
        float v[8] = {qa.x + ra.x, qa.y + ra.y, qa.z + ra.z, qa.w + ra.w,
                      qb.x + rb.x, qb.y + rb.y, qb.z + rb.z, qb.w + rb.w};
        bool iscos = (kc >= 16);
#pragma unroll
        for (int j = 0; j < 8; ++j) {
            float ang = tt * sdiv[(k0 + j) & 127];
            v[j] += iscos ? __cosf(ang) : __sinf(ang);
        }
        ushort_t hs[8], ls[8];
#pragma unroll
        for (int j = 0; j < 8; ++j) {
            ushort_t h = f2bf(v[j]);
            hs[j] = h;
            ls[j] = (ushort_t)(__float_as_uint(v[j] - bf2f(h)) >> 16);
        }
        uint4 hv, lv;
        hv.x = hs[0] | ((uint_t)hs[1] << 16); hv.y = hs[2] | ((uint_t)hs[3] << 16);
        hv.z = hs[4] | ((uint_t)hs[5] << 16); hv.w = hs[6] | ((uint_t)hs[7] << 16);
        lv.x = ls[0] | ((uint_t)ls[1] << 16); lv.y = ls[2] | ((uint_t)ls[3] << 16);
        lv.z = ls[4] | ((uint_t)ls[5] << 16); lv.w = ls[6] | ((uint_t)ls[7] << 16);
        int loff = ((w * 32 + kc) * 16 + pl) * 8;
        *(uint4*)(sAhi + loff) = hv;
        *(uint4*)(sAlo + loff) = lv;
    }
    __syncthreads();
    {
        f32x4 acc[4][2];
        f32x4 z4 = {0.f, 0.f, 0.f, 0.f};
#pragma unroll
        for (int mt = 0; mt < 4; ++mt)
#pragma unroll
            for (int nt = 0; nt < 2; ++nt) acc[mt][nt] = z4;
        bf16x8 bh[2][2], bl[2][2];
#pragma unroll
        for (int nt = 0; nt < 2; ++nt) {
            int off = (((w * 2 + nt) * 32 + kq) * 16 + nl) * 8;
            bh[0][nt] = *(const bf16x8*)(ws1h + off);
            bl[0][nt] = *(const bf16x8*)(ws1l + off);
        }
#pragma unroll
        for (int ks = 0; ks < 8; ++ks) {
            int cur = ks & 1, nxt = cur ^ 1;
            if (ks < 7) {
#pragma unroll
                for (int nt = 0; nt < 2; ++nt) {
                    int off = (((w * 2 + nt) * 32 + (ks + 1) * 4 + kq) * 16 + nl) * 8;
                    bh[nxt][nt] = *(const bf16x8*)(ws1h + off);
                    bl[nxt][nt] = *(const bf16x8*)(ws1l + off);
                }
            }
            bf16x8 ahi[4], alo[4];
#pragma unroll
            for (int mt = 0; mt < 4; ++mt) {
                int off = ((mt * 32 + ks * 4 + kq) * 16 + nl) * 8;
                ahi[mt] = *(const bf16x8*)&sAhi[off];
                alo[mt] = *(const bf16x8*)&sAlo[off];
            }
#pragma unroll
            for (int mt = 0; mt < 4; ++mt)
#pragma unroll
                for (int nt = 0; nt < 2; ++nt) {
                    acc[mt][nt] = MFMA16(ahi[mt], bh[cur][nt], acc[mt][nt]);
                    acc[mt][nt] = MFMA16(alo[mt], bh[cur][nt], acc[mt][nt]);
                    acc[mt][nt] = MFMA16(ahi[mt], bl[cur][nt], acc[mt][nt]);
                }
        }
        float ps[4][4];
#pragma unroll
        for (int mt = 0; mt < 4; ++mt)
#pragma unroll
            for (int r = 0; r < 4; ++r) ps[mt][r] = 0.f;
#pragma unroll
        for (int nt = 0; nt < 2; ++nt) {
            int ng = w * 32 + nt * 16 + nl;
            float chv = consth[ng], w2 = Ws2[ng];
#pragma unroll
            for (int mt = 0; mt < 4; ++mt)
#pragma unroll
                for (int r = 0; r < 4; ++r) {
                    float v = acc[mt][nt][r] + chv;
                    v = fmaxf(v, 0.2f * v);
                    ps[mt][r] += v * w2;
                }
        }
#pragma unroll
        for (int mt = 0; mt < 4; ++mt)
#pragma unroll
            for (int r = 0; r < 4; ++r) {
                float x = ps[mt][r];
                x += __shfl_xor(x, 1, 64);
                x += __shfl_xor(x, 2, 64);
                x += __shfl_xor(x, 4, 64);
                x += __shfl_xor(x, 8, 64);
                ps[mt][r] = x;
            }
        if (nl == 0) {
#pragma unroll
            for (int mt = 0; mt < 4; ++mt)
#pragma unroll
                for (int r = 0; r < 4; ++r)
                    atomicAdd(&sLogit[mt * 16 + kq * 4 + r], ps[mt][r]);
        }
    }
    __syncthreads();
    if (tid < 64) {
        int pp = p0 + tid;
        float lg = sLogit[tid] + bs2[0];
        float y = lg * 100.0f;
        y = fminf(fmaxf(y, -60.f), 60.f);
        float a = 1.0f / (1.0f + expf(-y));
        float av = a * mask[pp];
        out_ahat[pp] = av;
        sAh[tid] = av;
    }
    __syncthreads();
    {
        float ah[16];
#pragma unroll
        for (int mt = 0; mt < 4; ++mt)
#pragma unroll
            for (int r = 0; r < 4; ++r) ah[mt * 4 + r] = sAh[mt * 16 + kq * 4 + r];
        int bidx = p0 >> 11;
#pragma unroll 1
        for (int nblk = 0; nblk < 4; ++nblk) {
#pragma unroll 1
            for (int hf = 0; hf < 2; ++hf) {
                const ushort_t* gB = wa_b + (size_t)(w * 16 + nblk * 4 + hf * 2) * 4096 + lane * 8;
                f32x4 acc[4][2];
                bf16x8 bfr[2][2];
#pragma unroll
                for (int nt = 0; nt < 2; ++nt)
                    bfr[0][nt] = *(const bf16x8*)(gB + nt * 4096);
#pragma unroll
                for (int ks = 0; ks < 8; ++ks) {
                    int cur = ks & 1, nxt = cur ^ 1;
                    if (ks < 7) {
#pragma unroll
                        for (int nt = 0; nt < 2; ++nt)
                            bfr[nxt][nt] = *(const bf16x8*)(gB + nt * 4096 + (ks + 1) * 512);
                    }
                    bf16x8 a_[4];
#pragma unroll
                    for (int mt = 0; mt < 4; ++mt)
                        a_[mt] = *(const bf16x8*)&sAhi[((mt * 32 + ks * 4 + kq) * 16 + nl) * 8];
                    if (ks == 0) {
                        f32x4 z4 = {0.f, 0.f, 0.f, 0.f};
#pragma unroll
                        for (int mt = 0; mt < 4; ++mt)
#pragma unroll
                            for (int nt = 0; nt < 2; ++nt)
                                acc[mt][nt] = MFMA16(a_[mt], bfr[0][nt], z4);
                    } else {
#pragma unroll
                        for (int mt = 0; mt < 4; ++mt)
#pragma unroll
                            for (int nt = 0; nt < 2; ++nt)
                                acc[mt][nt] = MFMA16(a_[mt], bfr[cur][nt], acc[mt][nt]);
                    }
                }
#pragma unroll
                for (int nt = 0; nt < 2; ++nt) {
                    int ng = w * 256 + nblk * 64 + (hf * 2 + nt) * 16 + nl;
                    float ban = ba[ng];
                    float s = 0.f;
#pragma unroll
                    for (int mt = 0; mt < 4; ++mt)
#pragma unroll
                        for (int r = 0; r < 4; ++r) {
                            float v = acc[mt][nt][r] + ban;
                            v = fmaxf(v, 0.2f * v);
                            s += v * ah[mt * 4 + r];
                        }
                    s += __shfl_xor(s, 16, 64);
                    s += __shfl_xor(s, 32, 64);
                    if (kq == 0) atomicAdd(&u_i[bidx * 1024 + ng], s);
                }
            }
        }
    }
}

extern "C" void kernel_launch(void* const* d_in, const int* in_sizes, int n_in,
                              void* d_out, int out_size, void* d_ws, size_t ws_size,
                              hipStream_t stream) {
    const int* q_seq = (const int*)d_in[0];
    const int* r_seq = (const int*)d_in[1];
    const float* t_seq = (const float*)d_in[2];
    const float* mask = (const float*)d_in[3];
    const float* q_tab = (const float*)d_in[4];
    const float* r_tab = (const float*)d_in[5];
    const float* virt = (const float*)d_in[6];
    const float* Ws1 = (const float*)d_in[7];
    const float* bs1 = (const float*)d_in[8];
    const float* Ws2 = (const float*)d_in[9];
    const float* bs2 = (const float*)d_in[10];
    const float* Wa = (const float*)d_in[11];
    const float* ba = (const float*)d_in[12];
    float* out = (float*)d_out;

    // ws layout
    ushort_t* wa_b = (ushort_t*)d_ws;            // 1024*256 bf16 blocked (512 KB)
    ushort_t* ws1h = wa_b + 262144;              // 128*256 bf16 blocked (64 KB)
    ushort_t* ws1l = ws1h + 32768;               // 64 KB
    float* ch = (float*)(ws1l + 32768);          // 128 f32 (512 B)
    ushort_t* ghi = (ushort_t*)(ch + 128);       // 131072*256 bf16 blocked (64 MB)
    const size_t need = 524288 + 65536 + 65536 + 512 + 67108864;

    hipLaunchKernelGGL(k_prep, dim3(216), dim3(256), 0, stream,
                       Ws1, bs1, virt, Wa, ch, wa_b, ws1h, ws1l, out);
    if (ws_size >= need) {
        hipLaunchKernelGGL(k_embed, dim3(2048), dim3(256), 0, stream,
                           q_seq, r_seq, t_seq, q_tab, r_tab, ws1h, ws1l, ch, Ws2,
                           bs2, mask, out + 65536, ghi);
        hipLaunchKernelGGL(k_wa, dim3(2048), dim3(256), 0, stream,
                           ghi, out + 65536, wa_b, ba, out);
    } else {
        hipLaunchKernelGGL(k_fused_fb, dim3(2048), dim3(256), 0, stream,
                           q_seq, r_seq, t_seq, q_tab, r_tab, ws1h, ws1l, ch, Ws2,
                           bs2, mask, wa_b, ba, out + 65536, out);
    }
}